// Round 6
// baseline (85.027 us; speedup 1.0000x reference)
//
#include <hip/hip_runtime.h>

typedef float v4f __attribute__((ext_vector_type(4)));

#define NATOM 128
#define FEAT 128
#define FILT 128
#define BATCH 8

// Fused single kernel: block (b, ig, jq) recomputes its own s-tile
// (4 i-rows via W1 + bias, 32 j-rows via W2) into LDS, then runs the proven
// R5 broadcast-expand store phase. Kills the serial gemm kernel, its launch
// gap, and the s1/s2 round-trip; 537M-FMA recompute (~8us VALU) hides under
// the ~29us store-drain wall via 4-blocks/CU phase stagger.
// Compute mapping: 8 groups of 32 lanes; groups 0-3: {i-row g, j-rows 4g..4g+3}
// (needs W1+W2); groups 4-7: j-rows 16+4(g-4).. (W2 only). Branch on g is
// wave-uniform (wave = 2 adjacent groups).
__global__ __launch_bounds__(256) void fused_kernel(
    const float* __restrict__ sf, const float* __restrict__ dist,
    const float* __restrict__ W, const float* __restrict__ bias,
    float* __restrict__ out) {
  const int blk = blockIdx.x;
  const int jq = blk & 3;
  const int ig = (blk >> 2) & 31;
  const int b  = blk >> 7;
  const int i0 = ig * 4, j0 = jq * 32;
  const int tid = threadIdx.x;
  const int g  = tid >> 5;          // 0..7
  const int kq = (tid & 31) << 2;   // k: 0..124 step 4
  const int jl = tid >> 5;          // store-phase j-lane 0..7

  __shared__ float s_lds[36][FILT];  // rows 0..3 = s1 (i), 4..35 = s2 (j)
  __shared__ float dl[4 * 32 * 3];

  // Stage dist[b, i0..+4, j0..+32, :] early (consumed after the barrier).
  {
    const size_t dbase = ((size_t)(b * NATOM + i0) * NATOM + j0) * 3;
    for (int idx = tid; idx < 384; idx += 256) {
      const int ii = idx / 96, rem = idx - ii * 96;  // rem = jj*3+c
      dl[idx] = dist[dbase + (size_t)ii * NATOM * 3 + rem];
    }
  }

  // ---- Phase A: s-tile GEMM into LDS ----
  {
    const float* sfb = sf + (size_t)b * NATOM * FEAT;
    const float* W2k = W + FEAT * FILT + kq;
    v4f acc0 = {0,0,0,0}, acc1 = {0,0,0,0}, acc2 = {0,0,0,0},
        acc3 = {0,0,0,0}, acc4 = {0,0,0,0};

    if (g < 4) {
      const float* W1k = W + kq;
      const float* ri  = sfb + (i0 + g) * FEAT;
      const float* rj  = sfb + (j0 + 4 * g) * FEAT;
#pragma unroll 2
      for (int f = 0; f < FEAT; ++f) {
        const v4f w1 = *reinterpret_cast<const v4f*>(W1k + f * FILT);
        const v4f w2 = *reinterpret_cast<const v4f*>(W2k + f * FILT);
        acc0 += ri[f] * w1;
        acc1 += rj[f] * w2;
        acc2 += rj[FEAT + f] * w2;
        acc3 += rj[2 * FEAT + f] * w2;
        acc4 += rj[3 * FEAT + f] * w2;
      }
      acc0 += *reinterpret_cast<const v4f*>(bias + kq);
      *reinterpret_cast<v4f*>(&s_lds[g][kq]) = acc0;
      *reinterpret_cast<v4f*>(&s_lds[4 + 4 * g + 0][kq]) = acc1;
      *reinterpret_cast<v4f*>(&s_lds[4 + 4 * g + 1][kq]) = acc2;
      *reinterpret_cast<v4f*>(&s_lds[4 + 4 * g + 2][kq]) = acc3;
      *reinterpret_cast<v4f*>(&s_lds[4 + 4 * g + 3][kq]) = acc4;
    } else {
      const int jb = 16 + 4 * (g - 4);
      const float* rj = sfb + (j0 + jb) * FEAT;
#pragma unroll 2
      for (int f = 0; f < FEAT; ++f) {
        const v4f w2 = *reinterpret_cast<const v4f*>(W2k + f * FILT);
        acc1 += rj[f] * w2;
        acc2 += rj[FEAT + f] * w2;
        acc3 += rj[2 * FEAT + f] * w2;
        acc4 += rj[3 * FEAT + f] * w2;
      }
      *reinterpret_cast<v4f*>(&s_lds[4 + jb + 0][kq]) = acc1;
      *reinterpret_cast<v4f*>(&s_lds[4 + jb + 1][kq]) = acc2;
      *reinterpret_cast<v4f*>(&s_lds[4 + jb + 2][kq]) = acc3;
      *reinterpret_cast<v4f*>(&s_lds[4 + jb + 3][kq]) = acc4;
    }
  }

  __syncthreads();

  // ---- Phase B: broadcast-expand stores (proven R5 structure) ----
  v4f s1v[4];
#pragma unroll
  for (int ii = 0; ii < 4; ++ii)
    s1v[ii] = *reinterpret_cast<const v4f*>(&s_lds[ii][kq]);

  float* obase0 = out + (((size_t)(b * NATOM + i0) * NATOM + j0) * 3) * FILT;

#pragma unroll
  for (int jj0 = 0; jj0 < 32; jj0 += 8) {
    const int jj = jj0 + jl;
    const v4f s2v = *reinterpret_cast<const v4f*>(&s_lds[4 + jj][kq]);
#pragma unroll
    for (int ii = 0; ii < 4; ++ii) {
      const v4f p = s1v[ii] + s2v;
      const float d0 = dl[(ii * 32 + jj) * 3 + 0];
      const float d1 = dl[(ii * 32 + jj) * 3 + 1];
      const float d2 = dl[(ii * 32 + jj) * 3 + 2];
      float* o = obase0 + (size_t)ii * NATOM * 3 * FILT + (size_t)jj * 3 * FILT + kq;
      *reinterpret_cast<v4f*>(o) = p * d0;
      *reinterpret_cast<v4f*>(o + FILT) = p * d1;
      *reinterpret_cast<v4f*>(o + 2 * FILT) = p * d2;
    }
  }
}

extern "C" void kernel_launch(void* const* d_in, const int* in_sizes, int n_in,
                              void* d_out, int out_size, void* d_ws, size_t ws_size,
                              hipStream_t stream) {
  const float* sf   = (const float*)d_in[0];  // (8,128,128)
  const float* dist = (const float*)d_in[1];  // (8,128,128,3)
  const float* W    = (const float*)d_in[2];  // (256,128)
  const float* bias = (const float*)d_in[3];  // (1,128)
  float* out = (float*)d_out;                 // (8,128,128,3,128)

  fused_kernel<<<BATCH * 32 * 4, 256, 0, stream>>>(sf, dist, W, bias, out);
}

// Round 7
// 40.978 us; speedup vs baseline: 2.0749x; 2.0749x over previous
//
#include <hip/hip_runtime.h>

typedef float v4f __attribute__((ext_vector_type(4)));

#define NATOM 128
#define FEAT 128
#define FILT 128
#define BATCH 8

// Kernel 1: s-GEMM, 2 rows per block (512 blocks x 256 threads).
// thread = (which, k); each W element loaded once per block feeds 2 register
// accumulators (halves W L2 traffic vs 1-row: 128 -> 64 MB). sf rows staged
// in LDS, read back as v4f. Explicit unroll 4 keeps VGPRs modest (R4 lesson:
// full unroll + multi-row -> 256 VGPR, occupancy collapse).
__global__ __launch_bounds__(256) void s_gemm_kernel(
    const float* __restrict__ sf, const float* __restrict__ W,
    const float* __restrict__ bias, float* __restrict__ s1,
    float* __restrict__ s2) {
  const int r0 = blockIdx.x * 2;
  const int tid = threadIdx.x;
  const int k = tid & (FILT - 1);
  const int which = tid >> 7;  // 0 -> s1, 1 -> s2

  __shared__ float sfrow[2][FEAT];
  sfrow[tid >> 7][tid & 127] = sf[(r0 + (tid >> 7)) * FEAT + (tid & 127)];
  __syncthreads();

  const float* Wcol = W + which * FEAT * FILT + k;
  float a0 = 0.f, a1 = 0.f;
#pragma unroll 4
  for (int f4 = 0; f4 < FEAT; f4 += 4) {
    const v4f sv0 = *reinterpret_cast<const v4f*>(&sfrow[0][f4]);
    const v4f sv1 = *reinterpret_cast<const v4f*>(&sfrow[1][f4]);
#pragma unroll
    for (int fi = 0; fi < 4; ++fi) {
      const float w = Wcol[(f4 + fi) * FILT];
      a0 = fmaf(sv0[fi], w, a0);
      a1 = fmaf(sv1[fi], w, a1);
    }
  }

  const float bb = which ? 0.f : bias[k];
  float* dst = (which ? s2 : s1) + r0 * FILT + k;
  dst[0] = a0 + bb;
  dst[FILT] = a1 + bb;
}

// Kernel 2: out[b,i,j,c,k] = (s1[b,i,k] + s2[b,j,k]) * dist[b,i,j,c]
// R3 shape: 2048 blocks (b,i,j-half), 256 threads = 8 j-lanes x 32 k-quads.
// R6->R7 change: NO LDS dist staging / NO barrier — direct lane-uniform dist
// loads in-loop (1 scalar per 4 v4f stores, L1/L3-hit) remove the grid-wide
// stage+barrier bubble before the store storm. Plain stores (R3-proven),
// j-loop fully unrolled.
__global__ __launch_bounds__(256) void expand_kernel(
    const float* __restrict__ s1, const float* __restrict__ s2,
    const float* __restrict__ dist, float* __restrict__ out) {
  const int blk = blockIdx.x;
  const int bi = blk >> 1;         // b*N + i
  const int jh = blk & 1;          // which half of j
  const int b = bi >> 7;
  const int tid = threadIdx.x;
  const int kq = (tid & 31) << 2;  // k offset: 0..124 step 4
  const int jl = tid >> 5;         // 0..7

  const v4f s1v = *reinterpret_cast<const v4f*>(s1 + bi * FILT + kq);
  const float* s2base = s2 + ((size_t)(b << 7) + jh * 64) * FILT;
  const float* dbase = dist + ((size_t)bi * NATOM + jh * 64) * 3;
  float* obase = out + ((size_t)bi * NATOM + jh * 64) * 3 * FILT;

#pragma unroll
  for (int j0 = 0; j0 < 64; j0 += 8) {
    const int jloc = j0 + jl;
    const v4f s2v = *reinterpret_cast<const v4f*>(s2base + jloc * FILT + kq);
    const float d0 = dbase[jloc * 3 + 0];
    const float d1 = dbase[jloc * 3 + 1];
    const float d2 = dbase[jloc * 3 + 2];
    const v4f p = s1v + s2v;
    float* o = obase + (size_t)jloc * 3 * FILT + kq;
    *reinterpret_cast<v4f*>(o) = p * d0;
    *reinterpret_cast<v4f*>(o + FILT) = p * d1;
    *reinterpret_cast<v4f*>(o + 2 * FILT) = p * d2;
  }
}

extern "C" void kernel_launch(void* const* d_in, const int* in_sizes, int n_in,
                              void* d_out, int out_size, void* d_ws, size_t ws_size,
                              hipStream_t stream) {
  const float* sf   = (const float*)d_in[0];  // (8,128,128)
  const float* dist = (const float*)d_in[1];  // (8,128,128,3)
  const float* W    = (const float*)d_in[2];  // (256,128)
  const float* bias = (const float*)d_in[3];  // (1,128)
  float* out = (float*)d_out;                 // (8,128,128,3,128)

  float* s1 = (float*)d_ws;  // 1024*128 f32
  float* s2 = s1 + BATCH * NATOM * FILT;

  s_gemm_kernel<<<BATCH * NATOM / 2, 256, 0, stream>>>(sf, W, bias, s1, s2);
  expand_kernel<<<BATCH * NATOM * 2, 256, 0, stream>>>(s1, s2, dist, out);
}